// Round 11
// baseline (59.380 us; speedup 1.0000x reference)
//
#include <hip/hip_runtime.h>

// LLR denoiser, two-phase, atomic-free:
//   Phase 1 (llr_zs): per patch p, S_p = alpha_p * Zhat_p (16x16 ~ THS*G^{-1/2})
//            via register-resident Newton-Schulz; stored bf16 to ws (C-layout).
//   Phase 2 (llr_strip): block = 4-row x 128-px segment (32 cells).
//            KEY FIX (R11): no thread ever strides the 16 channel-planes
//            (1 MiB apart -> all planes alias one L1/L2 set; 16 same-set
//            streams/thread serialized every variant R2-R10 at ~35us while
//            zs's channel-per-lane loads ran 4x faster). Wave r streams
//            channels 4r..4r+3 -> LDS; matvec reads/writes LDS; wave r
//            streams results back out. All global I/O: <=4 streams/thread,
//            512B/instr coalesced.

#define NBATCH  2
#define NCH     16
#define HDIM    512
#define WDIM    512
#define NPH     127
#define NPW     127
#define NPATCH  (NBATCH * NPH * NPW)
#define NCELL   128
#define THS     0.1f
#define NSIT    8

typedef short bf16x8 __attribute__((ext_vector_type(8)));
typedef float f32x4  __attribute__((ext_vector_type(4)));

#define MFMA(a,b,c) __builtin_amdgcn_mfma_f32_16x16x32_bf16((a),(b),(c),0,0,0)

static __device__ inline short f2bf(float x) {
  return __builtin_bit_cast(short, (__bf16)x);   // native RNE convert
}
static __device__ inline float blo2f(unsigned int v) {
  return __builtin_bit_cast(float, v << 16);
}
static __device__ inline float bhi2f(unsigned int v) {
  return __builtin_bit_cast(float, v & 0xffff0000u);
}
static __device__ inline unsigned int pack2bf(float lo, float hi) {
  unsigned int a = (unsigned short)f2bf(lo);
  unsigned int b = (unsigned short)f2bf(hi);
  return (b << 16) | a;
}

// bijective XCD swizzle (m204) — used by llr_zs only
static __device__ inline int xcd_swz(int b, int nwg) {
  const int q = nwg >> 3, r = nwg & 7;
  const int x = b & 7, lo = b >> 3;
  return (x < r ? x * (q + 1) : r * (q + 1) + (x - r) * q) + lo;
}

static __device__ inline bf16x8 fragc(f32x4 v) {
  // symmetric-matrix C-layout -> MFMA A/B fragment (16 nonzero k-slots)
  bf16x8 r;
  r[0] = f2bf(v[0]); r[1] = f2bf(v[1]); r[2] = f2bf(v[2]); r[3] = f2bf(v[3]);
  r[4] = 0; r[5] = 0; r[6] = 0; r[7] = 0;
  return r;
}

// ---------------- Phase 1: per-patch scaled inverse-sqrt matrices ----------
// 256 threads = 4 waves = 4 consecutive patches per block.
#define ZS_NBLK ((NPATCH + 3) / 4)
__global__ __launch_bounds__(256) void llr_zs(const float* __restrict__ x,
                                              uint2* __restrict__ zs) {
  const int blk = xcd_swz(blockIdx.x, ZS_NBLK);
  const int pid = blk * 4 + (threadIdx.x >> 6);  // one wave per patch
  if (pid >= NPATCH) return;
  const int bi  = pid / (NPH * NPW);
  const int pr  = pid % (NPH * NPW);
  const int ph  = pr / NPW, pw = pr % NPW;
  const int h0  = ph * 4, w0 = pw * 4;
  const int l   = threadIdx.x & 63;
  const int j   = l & 15;                      // row/col id in 16x16 tiles
  const int u   = l >> 4;                      // k-group 0..3

  const size_t HW = (size_t)HDIM * WDIM;
  const float* xb = x + (size_t)bi * NCH * HW;

  // load M (16 channels x 64 pixels) in A-frag layout
  const float* pb = xb + (size_t)j * HW + (size_t)h0 * WDIM + w0;
  const int dh0 = (u >> 1), dw0 = 4 * (u & 1);
  float4 q0 = *(const float4*)(pb + (size_t)(dh0 + 0) * WDIM + dw0);
  float4 q1 = *(const float4*)(pb + (size_t)(dh0 + 2) * WDIM + dw0);
  float4 q2 = *(const float4*)(pb + (size_t)(dh0 + 4) * WDIM + dw0);
  float4 q3 = *(const float4*)(pb + (size_t)(dh0 + 6) * WDIM + dw0);

  bf16x8 m0, m1;
  m0[0]=f2bf(q0.x); m0[1]=f2bf(q0.y); m0[2]=f2bf(q0.z); m0[3]=f2bf(q0.w);
  m0[4]=f2bf(q1.x); m0[5]=f2bf(q1.y); m0[6]=f2bf(q1.z); m0[7]=f2bf(q1.w);
  m1[0]=f2bf(q2.x); m1[1]=f2bf(q2.y); m1[2]=f2bf(q2.z); m1[3]=f2bf(q2.w);
  m1[4]=f2bf(q3.x); m1[5]=f2bf(q3.y); m1[6]=f2bf(q3.z); m1[7]=f2bf(q3.w);

  // G = M M^T
  f32x4 g = {0.f, 0.f, 0.f, 0.f};
  g = MFMA(m0, m0, g);
  g = MFMA(m1, m1, g);

  // Frobenius norm^2 of G
  float s2 = g[0]*g[0] + g[1]*g[1] + g[2]*g[2] + g[3]*g[3];
  #pragma unroll
  for (int m = 32; m >= 1; m >>= 1) s2 += __shfl_xor(s2, m, 64);

  uint2 wv = {0u, 0u};
  if (s2 > 1e-20f) {
    const float invf  = rsqrtf(s2);            // 1/f, f = ||G||_F >= lmax
    const float gsc   = 2.0f * invf;           // normalize by t = f/2 (eig in (0,2])
    const float alpha = THS * sqrtf(gsc);      // THS / sqrt(t)

    // coupled Newton-Schulz: Y0 = G/t, Z0 = I; Z -> (G/t)^{-1/2}
    f32x4 Yc, Zc;
    #pragma unroll
    for (int r = 0; r < 4; ++r) {
      Yc[r] = g[r] * gsc;
      Zc[r] = (4 * u + r == j) ? 1.0f : 0.0f;
    }

    const f32x4 zero = {0.f, 0.f, 0.f, 0.f};
    for (int it = 0; it < NSIT - 1; ++it) {
      bf16x8 yF = fragc(Yc), zF = fragc(Zc);
      f32x4 t  = MFMA(zF, yF, zero);           // T = Z*Y
      bf16x8 tF = fragc(t);
      f32x4 py = MFMA(yF, tF, zero);           // Y*T
      f32x4 pz = MFMA(tF, zF, zero);           // T*Z
      #pragma unroll
      for (int r = 0; r < 4; ++r) {
        Yc[r] = 1.5f * Yc[r] - 0.5f * py[r];
        Zc[r] = 1.5f * Zc[r] - 0.5f * pz[r];
      }
    }
    { // final iteration: only Z needed
      bf16x8 yF = fragc(Yc), zF = fragc(Zc);
      f32x4 t  = MFMA(zF, yF, zero);
      bf16x8 tF = fragc(t);
      f32x4 pz = MFMA(tF, zF, zero);
      #pragma unroll
      for (int r = 0; r < 4; ++r) Zc[r] = 1.5f * Zc[r] - 0.5f * pz[r];
    }

    wv.x = pack2bf(alpha * Zc[0], alpha * Zc[1]);
    wv.y = pack2bf(alpha * Zc[2], alpha * Zc[3]);
  }
  zs[(size_t)pid * 64 + l] = wv;               // coalesced 512B per patch
}

// ---------------- Phase 2: segment apply via LDS channel-exchange ----------
// Block = (bi, ci, seg): 4 rows x 128 px = 32 cells. 256 threads, 4 waves.
//   A: wave r streams x channels 4r..4r+3 (all 4 rows) -> Xf LDS;
//      zs gather (branch-free, clamped) -> Wl LDS (rotated layout).
//   B: thread (r, q2) reads its pixel-f2's 16 channels from Xf (b64,
//      conflict-free), matvec vs Wl, results -> Xf.
//   C: wave r streams channels 4r..4r+3 from Xf to out (coalesced).
#define ST_SEG  4
#define ST_NBLK (NBATCH * NCELL * ST_SEG)   // 1024
__global__ __launch_bounds__(256, 3) void llr_strip(const float* __restrict__ x,
                                                    const uint2* __restrict__ zs,
                                                    float* __restrict__ out) {
  __shared__ unsigned int Wl[32 * 128];        // 16 KB
  __shared__ float Xf[16 * 4 * 128];           // 32 KB: [ch][row][px]

  const int bid = blockIdx.x;                  // no swizzle on phase 2
  const int seg = bid & 3;
  const int ci  = (bid >> 2) & 127;
  const int bi  = bid >> 9;
  const int t   = threadIdx.x;
  const int r   = t >> 6;                      // wave id
  const int l   = t & 63;                      // lane

  const size_t HW = (size_t)HDIM * WDIM;
  const float* xb = x + (size_t)bi * NCH * HW;
  float* ob = out + (size_t)bi * NCH * HW;
  const int wbase = seg * 128;
  const int h0 = 4 * ci;

  // ---- A1: x -> regs. Wave r: channels 4r..4r+3, rows 0..3; each instr
  // covers 64 lanes x 8B = 512B contiguous; only 4 plane-streams per thread.
  float2 xr[4][4];
  #pragma unroll
  for (int rho = 0; rho < 4; ++rho)
    #pragma unroll
    for (int i = 0; i < 4; ++i)
      xr[i][rho] = *(const float2*)(xb + (size_t)(4 * r + i) * HW
                                       + (size_t)(h0 + rho) * WDIM + wbase + 2 * l);

  // ---- A2: zs gather -> Wl (branch-free clamped loads, uniform masking)
  {
    const int u = l >> 4, j = l & 15;
    const float cnth = 2.0f - (ci == 0) - (ci == NCELL - 1);
    const uint2* zb = zs + (size_t)bi * NPH * NPW * 64;
    const int ph0 = (ci > 0) ? ci - 1 : 0;
    const int ph1 = (ci < NPH) ? ci : NPH - 1;
    const bool vh0 = (ci > 0), vh1 = (ci < NPH);

    #pragma unroll
    for (int half = 0; half < 2; ++half) {
      uint2 zv[4][4];
      int   cja[4];
      #pragma unroll
      for (int i = 0; i < 4; ++i) {
        const int c  = (half * 4 + i) * 4 + r; // cell 0..31 (wave-uniform)
        const int cj = seg * 32 + c;
        cja[i] = cj;
        const int pw0 = (cj > 0) ? cj - 1 : 0;
        const int pw1 = (cj < NPW) ? cj : NPW - 1;
        zv[i][0] = zb[((size_t)ph0 * NPW + pw0) * 64 + l];
        zv[i][1] = zb[((size_t)ph0 * NPW + pw1) * 64 + l];
        zv[i][2] = zb[((size_t)ph1 * NPW + pw0) * 64 + l];
        zv[i][3] = zb[((size_t)ph1 * NPW + pw1) * 64 + l];
      }
      #pragma unroll
      for (int i = 0; i < 4; ++i) {
        const int c  = (half * 4 + i) * 4 + r;
        const int cj = cja[i];
        const bool vw0 = (cj > 0), vw1 = (cj < NPW);
        float a0 = 0.f, a1 = 0.f, a2 = 0.f, a3 = 0.f;
        #pragma unroll
        for (int k = 0; k < 4; ++k) {
          const bool ok = (k < 2 ? vh0 : vh1) && ((k & 1) == 0 ? vw0 : vw1);
          uint2 z = zv[i][k];
          if (!ok) { z.x = 0u; z.y = 0u; }
          a0 += blo2f(z.x); a1 += bhi2f(z.x);
          a2 += blo2f(z.y); a3 += bhi2f(z.y);
        }
        const float cntw = 2.0f - (cj == 0) - (cj == NCELL - 1);
        const float s = 1.0f / (cnth * cntw);
        const int base = c * 128;
        const int u0 = 8 * u + (j >> 2);       // pair 2u
        const int u1 = u0 + 4;                 // pair 2u+1
        Wl[base + (((u0 + c) & 31) << 2) + (j & 3)] = pack2bf(s * a0, s * a1);
        Wl[base + (((u1 + c) & 31) << 2) + (j & 3)] = pack2bf(s * a2, s * a3);
      }
    }
  }

  // ---- A3: x regs -> Xf
  #pragma unroll
  for (int i = 0; i < 4; ++i)
    #pragma unroll
    for (int rho = 0; rho < 4; ++rho)
      *(float2*)&Xf[((4 * r + i) * 4 + rho) * 128 + 2 * l] = xr[i][rho];
  __syncthreads();                             // #1: Xf/Wl complete

  // ---- B1: read this pixel's 16 channels from LDS
  const int q2 = l;                            // f2-column 0..63
  float2 xl[16];
  #pragma unroll
  for (int e = 0; e < 16; ++e)
    xl[e] = *(const float2*)&Xf[(e * 4 + r) * 128 + 2 * q2];
  __syncthreads();                             // #2: Xf free for results

  // ---- B2: matvec out = x - W*x
  const int cl = q2 >> 1;                      // lane's cell 0..31
  float2 ov[16];
  #pragma unroll
  for (int cp = 0; cp < 8; ++cp) {
    float2 d0 = {0.f, 0.f};
    float2 d1 = {0.f, 0.f};
    #pragma unroll
    for (int k = 0; k < 4; ++k) {
      const uint4 V = *(const uint4*)&Wl[cl * 128 + (((4 * cp + k + cl) & 31) << 2)];
      const unsigned int va[4] = {V.x, V.y, V.z, V.w};
      #pragma unroll
      for (int c = 0; c < 4; ++c) {
        const int e = 4 * k + c;
        const float wlo = blo2f(va[c]);        // out-ch 2cp,   in-ch e
        const float whi = bhi2f(va[c]);        // out-ch 2cp+1, in-ch e
        d0.x += wlo * xl[e].x; d0.y += wlo * xl[e].y;
        d1.x += whi * xl[e].x; d1.y += whi * xl[e].y;
      }
    }
    const int c0 = 2 * cp, c1 = 2 * cp + 1;
    ov[c0].x = xl[c0].x - d0.x; ov[c0].y = xl[c0].y - d0.y;
    ov[c1].x = xl[c1].x - d1.x; ov[c1].y = xl[c1].y - d1.y;
  }

  // ---- B3: results -> Xf
  #pragma unroll
  for (int e = 0; e < 16; ++e)
    *(float2*)&Xf[(e * 4 + r) * 128 + 2 * q2] = ov[e];
  __syncthreads();                             // #3: results complete

  // ---- C: wave r streams channels 4r..4r+3 to out (512B/instr coalesced)
  #pragma unroll
  for (int i = 0; i < 4; ++i)
    #pragma unroll
    for (int rho = 0; rho < 4; ++rho) {
      float2 v = *(const float2*)&Xf[((4 * r + i) * 4 + rho) * 128 + 2 * l];
      *(float2*)(ob + (size_t)(4 * r + i) * HW
                    + (size_t)(h0 + rho) * WDIM + wbase + 2 * l) = v;
    }
}

extern "C" void kernel_launch(void* const* d_in, const int* in_sizes, int n_in,
                              void* d_out, int out_size, void* d_ws, size_t ws_size,
                              hipStream_t stream) {
  const float* x = (const float*)d_in[0];
  float* out = (float*)d_out;
  uint2* zs = (uint2*)d_ws;                    // 32258*512B = 16.5 MB

  llr_zs<<<dim3(ZS_NBLK), dim3(256), 0, stream>>>(x, zs);
  llr_strip<<<dim3(ST_NBLK), dim3(256), 0, stream>>>(x, zs, out);
}

// Round 12
// 49.986 us; speedup vs baseline: 1.1879x; 1.1879x over previous
//
#include <hip/hip_runtime.h>

// LLR denoiser, two-phase, atomic-free:
//   Phase 1 (llr_zs): per patch p, S_p = alpha_p * Zhat_p (16x16 ~ THS*G^{-1/2})
//            via register-resident Newton-Schulz; stored bf16 to ws (C-layout).
//   Phase 2 (llr_strip): block = 4 rows x 64 px (16 cells). R12 insight: all
//            apply variants sat at VGPR 84-92 -> HW caps 16 waves/CU (halves
//            at >64 VGPR); latency-bound kernel needs 32 waves/CU. This
//            version is designed to fit 64 VGPR: scalar xv[16], shared
//            rowsum gather (17 slots x 2 loads), launch_bounds(256,8).

#define NBATCH  2
#define NCH     16
#define HDIM    512
#define WDIM    512
#define NPH     127
#define NPW     127
#define NPATCH  (NBATCH * NPH * NPW)
#define NCELL   128
#define THS     0.1f
#define NSIT    8

typedef short bf16x8 __attribute__((ext_vector_type(8)));
typedef float f32x4  __attribute__((ext_vector_type(4)));

#define MFMA(a,b,c) __builtin_amdgcn_mfma_f32_16x16x32_bf16((a),(b),(c),0,0,0)

static __device__ inline short f2bf(float x) {
  return __builtin_bit_cast(short, (__bf16)x);   // native RNE convert
}
static __device__ inline float blo2f(unsigned int v) {
  return __builtin_bit_cast(float, v << 16);
}
static __device__ inline float bhi2f(unsigned int v) {
  return __builtin_bit_cast(float, v & 0xffff0000u);
}
static __device__ inline unsigned int pack2bf(float lo, float hi) {
  unsigned int a = (unsigned short)f2bf(lo);
  unsigned int b = (unsigned short)f2bf(hi);
  return (b << 16) | a;
}

// bijective XCD swizzle (m204) — used by llr_zs only
static __device__ inline int xcd_swz(int b, int nwg) {
  const int q = nwg >> 3, r = nwg & 7;
  const int x = b & 7, lo = b >> 3;
  return (x < r ? x * (q + 1) : r * (q + 1) + (x - r) * q) + lo;
}

static __device__ inline bf16x8 fragc(f32x4 v) {
  // symmetric-matrix C-layout -> MFMA A/B fragment (16 nonzero k-slots)
  bf16x8 r;
  r[0] = f2bf(v[0]); r[1] = f2bf(v[1]); r[2] = f2bf(v[2]); r[3] = f2bf(v[3]);
  r[4] = 0; r[5] = 0; r[6] = 0; r[7] = 0;
  return r;
}

// ---------------- Phase 1: per-patch scaled inverse-sqrt matrices ----------
// 256 threads = 4 waves = 4 consecutive patches per block.
#define ZS_NBLK ((NPATCH + 3) / 4)
__global__ __launch_bounds__(256) void llr_zs(const float* __restrict__ x,
                                              uint2* __restrict__ zs) {
  const int blk = xcd_swz(blockIdx.x, ZS_NBLK);
  const int pid = blk * 4 + (threadIdx.x >> 6);  // one wave per patch
  if (pid >= NPATCH) return;
  const int bi  = pid / (NPH * NPW);
  const int pr  = pid % (NPH * NPW);
  const int ph  = pr / NPW, pw = pr % NPW;
  const int h0  = ph * 4, w0 = pw * 4;
  const int l   = threadIdx.x & 63;
  const int j   = l & 15;                      // row/col id in 16x16 tiles
  const int u   = l >> 4;                      // k-group 0..3

  const size_t HW = (size_t)HDIM * WDIM;
  const float* xb = x + (size_t)bi * NCH * HW;

  // load M (16 channels x 64 pixels) in A-frag layout
  const float* pb = xb + (size_t)j * HW + (size_t)h0 * WDIM + w0;
  const int dh0 = (u >> 1), dw0 = 4 * (u & 1);
  float4 q0 = *(const float4*)(pb + (size_t)(dh0 + 0) * WDIM + dw0);
  float4 q1 = *(const float4*)(pb + (size_t)(dh0 + 2) * WDIM + dw0);
  float4 q2 = *(const float4*)(pb + (size_t)(dh0 + 4) * WDIM + dw0);
  float4 q3 = *(const float4*)(pb + (size_t)(dh0 + 6) * WDIM + dw0);

  bf16x8 m0, m1;
  m0[0]=f2bf(q0.x); m0[1]=f2bf(q0.y); m0[2]=f2bf(q0.z); m0[3]=f2bf(q0.w);
  m0[4]=f2bf(q1.x); m0[5]=f2bf(q1.y); m0[6]=f2bf(q1.z); m0[7]=f2bf(q1.w);
  m1[0]=f2bf(q2.x); m1[1]=f2bf(q2.y); m1[2]=f2bf(q2.z); m1[3]=f2bf(q2.w);
  m1[4]=f2bf(q3.x); m1[5]=f2bf(q3.y); m1[6]=f2bf(q3.z); m1[7]=f2bf(q3.w);

  // G = M M^T
  f32x4 g = {0.f, 0.f, 0.f, 0.f};
  g = MFMA(m0, m0, g);
  g = MFMA(m1, m1, g);

  // Frobenius norm^2 of G
  float s2 = g[0]*g[0] + g[1]*g[1] + g[2]*g[2] + g[3]*g[3];
  #pragma unroll
  for (int m = 32; m >= 1; m >>= 1) s2 += __shfl_xor(s2, m, 64);

  uint2 wv = {0u, 0u};
  if (s2 > 1e-20f) {
    const float invf  = rsqrtf(s2);            // 1/f, f = ||G||_F >= lmax
    const float gsc   = 2.0f * invf;           // normalize by t = f/2 (eig in (0,2])
    const float alpha = THS * sqrtf(gsc);      // THS / sqrt(t)

    // coupled Newton-Schulz: Y0 = G/t, Z0 = I; Z -> (G/t)^{-1/2}
    f32x4 Yc, Zc;
    #pragma unroll
    for (int r = 0; r < 4; ++r) {
      Yc[r] = g[r] * gsc;
      Zc[r] = (4 * u + r == j) ? 1.0f : 0.0f;
    }

    const f32x4 zero = {0.f, 0.f, 0.f, 0.f};
    for (int it = 0; it < NSIT - 1; ++it) {
      bf16x8 yF = fragc(Yc), zF = fragc(Zc);
      f32x4 t  = MFMA(zF, yF, zero);           // T = Z*Y
      bf16x8 tF = fragc(t);
      f32x4 py = MFMA(yF, tF, zero);           // Y*T
      f32x4 pz = MFMA(tF, zF, zero);           // T*Z
      #pragma unroll
      for (int r = 0; r < 4; ++r) {
        Yc[r] = 1.5f * Yc[r] - 0.5f * py[r];
        Zc[r] = 1.5f * Zc[r] - 0.5f * pz[r];
      }
    }
    { // final iteration: only Z needed
      bf16x8 yF = fragc(Yc), zF = fragc(Zc);
      f32x4 t  = MFMA(zF, yF, zero);
      bf16x8 tF = fragc(t);
      f32x4 pz = MFMA(tF, zF, zero);
      #pragma unroll
      for (int r = 0; r < 4; ++r) Zc[r] = 1.5f * Zc[r] - 0.5f * pz[r];
    }

    wv.x = pack2bf(alpha * Zc[0], alpha * Zc[1]);
    wv.y = pack2bf(alpha * Zc[2], alpha * Zc[3]);
  }
  zs[(size_t)pid * 64 + l] = wv;               // coalesced 512B per patch
}

// ---------------- Phase 2: segment apply, 64-VGPR design -------------------
// Block = (bi, ci, seg): 4 rows x 64 px = 16 cells. 256 threads, 4 waves:
//   thread (r = t>>6, q = t&63) owns pixel (h = 4ci+r, w = seg*64+q), 16 ch.
// Gather: 17 rowsum slots s (patch col pw = seg*16-1+s), slot s by wave s%4;
//   rs[s] = maskedZ(ci-1,pw) + maskedZ(ci,pw), bf16-packed in LDS.
// Phase B: W(cell cj) = rs[cl] + rs[cl+1]; out = x - W*x/(cnth*cntw).
// LDS slot layout: dword d2 = 16p + e (pair p = out-ch 2p,2p+1; in-ch e) at
//   RS[s*132 + d2]; gather lane (u = l>>4, j = l&15) writes d2 = 32u+j and
//   32u+16+j. Phase B uint4 covers e = 4k..4k+3 of pair p.
#define ST_SEG  8
#define ST_NBLK (NBATCH * NCELL * ST_SEG)   // 2048 -> 8 blocks/CU
__global__ __launch_bounds__(256, 8) void llr_strip(const float* __restrict__ x,
                                                    const uint2* __restrict__ zs,
                                                    float* __restrict__ out) {
  __shared__ unsigned int RS[17 * 132];        // 8976 B

  const int bid = blockIdx.x;
  const int seg = bid & 7;
  const int ci  = (bid >> 3) & 127;
  const int bi  = bid >> 10;
  const int t   = threadIdx.x;
  const int r   = t >> 6;                      // wave id = pixel row 0..3
  const int l   = t & 63;                      // lane = pixel column in segment

  const size_t HW = (size_t)HDIM * WDIM;
  const float* xb = x + (size_t)bi * NCH * HW;
  float* ob = out + (size_t)bi * NCH * HW;

  // ---- prefetch x: 16 coalesced dword loads (256B/wave-instr), issued first
  const int h   = 4 * ci + r;
  const int wpx = seg * 64 + l;
  const float* px = xb + (size_t)h * WDIM + wpx;
  float xv[16];
  #pragma unroll
  for (int e = 0; e < 16; ++e) xv[e] = px[(size_t)e * HW];

  // ---- gather: rowsum slots -> LDS (slot s = wave r, r+4, ..., <=5 rounds)
  {
    const int u = l >> 4, j = l & 15;
    const uint2* zb = zs + (size_t)bi * NPH * NPW * 64;
    const bool vh0 = (ci > 0), vh1 = (ci < NPH);
    const int ph0c = vh0 ? ci - 1 : 0;
    const int ph1c = vh1 ? ci : NPH - 1;
    for (int s = r; s < 17; s += 4) {
      const int pw = seg * 16 - 1 + s;
      const bool vw = ((unsigned)pw <= (unsigned)(NPW - 1));
      const int pwc = vw ? pw : 0;
      uint2 z0 = zb[((size_t)ph0c * NPW + pwc) * 64 + l];
      uint2 z1 = zb[((size_t)ph1c * NPW + pwc) * 64 + l];
      if (!(vw && vh0)) { z0.x = 0u; z0.y = 0u; }
      if (!(vw && vh1)) { z1.x = 0u; z1.y = 0u; }
      const float a0 = blo2f(z0.x) + blo2f(z1.x);
      const float a1 = bhi2f(z0.x) + bhi2f(z1.x);
      const float a2 = blo2f(z0.y) + blo2f(z1.y);
      const float a3 = bhi2f(z0.y) + bhi2f(z1.y);
      RS[s * 132 + 32 * u + j]      = pack2bf(a0, a1);  // pair 2u
      RS[s * 132 + 32 * u + 16 + j] = pack2bf(a2, a3);  // pair 2u+1
    }
  }
  __syncthreads();

  // ---- phase B: out = x - (rs[cl]+rs[cl+1]) * x / cnt
  const int cl = l >> 2;                       // cell-local 0..15
  const int cj = seg * 16 + cl;                // global cell col 0..127
  const float cnth = 2.0f - (ci == 0) - (ci == NCELL - 1);
  const float cntw = 2.0f - (cj == 0) - (cj == NCELL - 1);
  const float sc = 1.0f / (cnth * cntw);

  float* po = ob + (size_t)h * WDIM + wpx;
  #pragma unroll
  for (int p = 0; p < 8; ++p) {
    float d0 = 0.f, d1 = 0.f;
    #pragma unroll
    for (int k = 0; k < 4; ++k) {
      const uint4 A = *(const uint4*)&RS[cl * 132 + 16 * p + 4 * k];
      const uint4 B = *(const uint4*)&RS[(cl + 1) * 132 + 16 * p + 4 * k];
      const unsigned int aa[4] = {A.x, A.y, A.z, A.w};
      const unsigned int bb[4] = {B.x, B.y, B.z, B.w};
      #pragma unroll
      for (int c = 0; c < 4; ++c) {
        const int e = 4 * k + c;
        const float wlo = blo2f(aa[c]) + blo2f(bb[c]);
        const float whi = bhi2f(aa[c]) + bhi2f(bb[c]);
        d0 += wlo * xv[e];
        d1 += whi * xv[e];
      }
    }
    po[(size_t)(2 * p) * HW]     = xv[2 * p]     - sc * d0;
    po[(size_t)(2 * p + 1) * HW] = xv[2 * p + 1] - sc * d1;
  }
}

extern "C" void kernel_launch(void* const* d_in, const int* in_sizes, int n_in,
                              void* d_out, int out_size, void* d_ws, size_t ws_size,
                              hipStream_t stream) {
  const float* x = (const float*)d_in[0];
  float* out = (float*)d_out;
  uint2* zs = (uint2*)d_ws;                    // 32258*512B = 16.5 MB

  llr_zs<<<dim3(ZS_NBLK), dim3(256), 0, stream>>>(x, zs);
  llr_strip<<<dim3(ST_NBLK), dim3(256), 0, stream>>>(x, zs, out);
}